// Round 1
// baseline (8648.863 us; speedup 1.0000x reference)
//
#include <hip/hip_runtime.h>
#include <math.h>

// GCN: 2× (scatter-aggregate with symmetric norm) on N=500k, E=16M.
// Trick 1: norm factored as dinv[dst]*Σ(g[src]) with g = feat*dinv.
// Trick 2: W applied AFTER aggregation (linearity) -> both scatters move 5 floats/edge.
// ws layout: dinv[N] | g[5N] (g1 then overwritten by g2) | acc[5N] (acc1 then re-zeroed -> acc2)

#define FIN 5
#define FHID 5
#define FOUT 8

__global__ void k_init_deg(float* __restrict__ deg, int n) {
    int i = blockIdx.x * blockDim.x + threadIdx.x;
    if (i < n) deg[i] = 1.0f;  // self-loop contributes 1 to degree
}

__global__ void k_count_deg(const int* __restrict__ dst, float* __restrict__ deg, int e) {
    int i = blockIdx.x * blockDim.x + threadIdx.x;
    if (i < e) atomicAdd(&deg[dst[i]], 1.0f);
}

// dinv = rsqrt(deg) in place; g1 = x * dinv (pre-scaled features)
__global__ void k_finish_deg_g1(const float* __restrict__ x, float* __restrict__ dinv,
                                float* __restrict__ g1, int n) {
    int i = blockIdx.x * blockDim.x + threadIdx.x;
    if (i >= n) return;
    float d = rsqrtf(dinv[i]);
    dinv[i] = d;
#pragma unroll
    for (int f = 0; f < FIN; ++f) g1[(size_t)i * FIN + f] = x[(size_t)i * FIN + f] * d;
}

// acc[dst] += g[src], 5 floats per edge
__global__ void k_scatter5(const int* __restrict__ src, const int* __restrict__ dst,
                           const float* __restrict__ g, float* __restrict__ acc, int e) {
    int i = blockIdx.x * blockDim.x + threadIdx.x;
    if (i >= e) return;
    int s = src[i], d = dst[i];
    float v0 = g[(size_t)s * 5 + 0];
    float v1 = g[(size_t)s * 5 + 1];
    float v2 = g[(size_t)s * 5 + 2];
    float v3 = g[(size_t)s * 5 + 3];
    float v4 = g[(size_t)s * 5 + 4];
    float* a = acc + (size_t)d * 5;
    atomicAdd(a + 0, v0);
    atomicAdd(a + 1, v1);
    atomicAdd(a + 2, v2);
    atomicAdd(a + 3, v3);
    atomicAdd(a + 4, v4);
}

// node update after layer-1 scatter:
//   v = (acc1 + g1) * dinv          (include self-loop term g1[i]*dinv)
//   h = relu(v @ W1 + b1)
//   g2 = h * dinv   (written over g1)
//   acc1 = 0        (becomes acc2)
__global__ void k_update1(const float* __restrict__ dinv, float* __restrict__ g,
                          float* __restrict__ acc, const float* __restrict__ W1,
                          const float* __restrict__ b1, int n) {
    int i = blockIdx.x * blockDim.x + threadIdx.x;
    if (i >= n) return;
    float d = dinv[i];
    float v[FIN];
#pragma unroll
    for (int f = 0; f < FIN; ++f) {
        size_t idx = (size_t)i * FIN + f;
        v[f] = (acc[idx] + g[idx]) * d;
        acc[idx] = 0.0f;
    }
    float h[FHID];
#pragma unroll
    for (int j = 0; j < FHID; ++j) {
        float s = b1[j];
#pragma unroll
        for (int k = 0; k < FIN; ++k) s += v[k] * W1[k * FHID + j];
        h[j] = fmaxf(s, 0.0f) * d;  // relu then pre-scale for layer-2 scatter
    }
#pragma unroll
    for (int j = 0; j < FHID; ++j) g[(size_t)i * FHID + j] = h[j];
}

// final: v = (acc2 + g2) * dinv ; o = v @ W2 + b2 ; out = log_softmax(o)
__global__ void k_update2(const float* __restrict__ dinv, const float* __restrict__ g,
                          const float* __restrict__ acc, const float* __restrict__ W2,
                          const float* __restrict__ b2, float* __restrict__ out, int n) {
    int i = blockIdx.x * blockDim.x + threadIdx.x;
    if (i >= n) return;
    float d = dinv[i];
    float v[FHID];
#pragma unroll
    for (int f = 0; f < FHID; ++f) {
        size_t idx = (size_t)i * FHID + f;
        v[f] = (acc[idx] + g[idx]) * d;
    }
    float o[FOUT];
    float m = -1e30f;
#pragma unroll
    for (int j = 0; j < FOUT; ++j) {
        float s = b2[j];
#pragma unroll
        for (int k = 0; k < FHID; ++k) s += v[k] * W2[k * FOUT + j];
        o[j] = s;
        m = fmaxf(m, s);
    }
    float ssum = 0.0f;
#pragma unroll
    for (int j = 0; j < FOUT; ++j) ssum += expf(o[j] - m);
    float lse = m + logf(ssum);
#pragma unroll
    for (int j = 0; j < FOUT; ++j) out[(size_t)i * FOUT + j] = o[j] - lse;
}

extern "C" void kernel_launch(void* const* d_in, const int* in_sizes, int n_in,
                              void* d_out, int out_size, void* d_ws, size_t ws_size,
                              hipStream_t stream) {
    const float* x  = (const float*)d_in[0];
    const int*   ei = (const int*)d_in[1];
    const float* W1 = (const float*)d_in[2];
    const float* b1 = (const float*)d_in[3];
    const float* W2 = (const float*)d_in[4];
    const float* b2 = (const float*)d_in[5];

    const int n = in_sizes[0] / FIN;   // 500,000
    const int e = in_sizes[1] / 2;     // 16,000,000
    const int* src = ei;               // edge_index[0]
    const int* dst = ei + e;           // edge_index[1]

    float* dinv = (float*)d_ws;               // n
    float* g    = dinv + n;                   // 5n  (g1, later g2)
    float* acc  = g + (size_t)5 * n;          // 5n  (acc1, later acc2)

    const int B = 256;
    const int gn = (n + B - 1) / B;
    const int ge = (e + B - 1) / B;

    hipMemsetAsync(acc, 0, (size_t)5 * n * sizeof(float), stream);
    k_init_deg<<<gn, B, 0, stream>>>(dinv, n);
    k_count_deg<<<ge, B, 0, stream>>>(dst, dinv, e);
    k_finish_deg_g1<<<gn, B, 0, stream>>>(x, dinv, g, n);
    k_scatter5<<<ge, B, 0, stream>>>(src, dst, g, acc, e);
    k_update1<<<gn, B, 0, stream>>>(dinv, g, acc, W1, b1, n);
    k_scatter5<<<ge, B, 0, stream>>>(src, dst, g, acc, e);
    k_update2<<<gn, B, 0, stream>>>(dinv, g, acc, W2, b2, (float*)d_out, n);
}

// Round 2
// 2367.387 us; speedup vs baseline: 3.6533x; 3.6533x over previous
//
#include <hip/hip_runtime.h>
#include <math.h>

// GCN 2-layer, N=500k nodes, E=16M edges, F 5->5->8.
// R2 strategy: eliminate float atomics entirely via CSR + gather aggregation.
//   - deg histogram (needed for norm anyway) = CSR row counts, int atomics
//   - position pass: 16M int atomics -> sorted_src
//   - both layers: gather over rows, 16 lanes/node, shfl reduce, fused
//     dense transform + relu / log_softmax epilogue. No float atomics.
//   - hist/cursor split into 8 edge-chunk replicas to spread LLC line
//     contention (diagnostic for the 20 G atomics/s ceiling seen in R1).
// Fallback to R1 atomic-scatter path if ws_size too small.

#define FIN 5
#define FHID 5
#define FOUT 8
#define GST 8       // padded feature stride (32 B) for single-line gathers
#define NCHUNK 8

// ---------------- main path kernels ----------------

__global__ void k_hist(const int* __restrict__ dst, int* __restrict__ cnt,
                       int n, int e, int chunk_div) {
    int i = blockIdx.x * blockDim.x + threadIdx.x;
    if (i >= e) return;
    int c = i / chunk_div;
    atomicAdd(&cnt[(size_t)c * n + dst[i]], 1);
}

// per-node: total real-edge count, dinv, pre-scaled g1 (stride GST)
__global__ void k_sumdeg(const int* __restrict__ cnt, const float* __restrict__ x,
                         int* __restrict__ t, float* __restrict__ dinv,
                         float* __restrict__ g1, int n) {
    int i = blockIdx.x * blockDim.x + threadIdx.x;
    if (i >= n) return;
    int tot = 0;
#pragma unroll
    for (int c = 0; c < NCHUNK; ++c) tot += cnt[(size_t)c * n + i];
    t[i] = tot;
    float d = rsqrtf((float)(tot + 1));  // +1 self-loop
    dinv[i] = d;
#pragma unroll
    for (int f = 0; f < FIN; ++f) g1[(size_t)i * GST + f] = x[(size_t)i * FIN + f] * d;
}

// block-local exclusive scan of t -> rowptr(local), block sums -> partial
__global__ void k_scan1(const int* __restrict__ t, int* __restrict__ rowptr,
                        int* __restrict__ partial, int n) {
    __shared__ int sh[256];
    int tx = threadIdx.x;
    int i = blockIdx.x * 256 + tx;
    int v = (i < n) ? t[i] : 0;
    sh[tx] = v;
    __syncthreads();
    for (int off = 1; off < 256; off <<= 1) {
        int add = (tx >= off) ? sh[tx - off] : 0;
        __syncthreads();
        sh[tx] += add;
        __syncthreads();
    }
    if (i < n) rowptr[i] = sh[tx] - v;  // exclusive within block
    if (tx == 255) partial[blockIdx.x] = sh[255];
}

// single-block exclusive scan of partial[nb] in place
__global__ void k_scan2(int* __restrict__ partial, int nb) {
    __shared__ int sh[256];
    __shared__ int carry;
    int tx = threadIdx.x;
    if (tx == 0) carry = 0;
    __syncthreads();
    for (int base = 0; base < nb; base += 256) {
        int i = base + tx;
        int v = (i < nb) ? partial[i] : 0;
        int c0 = carry;
        sh[tx] = v;
        __syncthreads();
        for (int off = 1; off < 256; off <<= 1) {
            int add = (tx >= off) ? sh[tx - off] : 0;
            __syncthreads();
            sh[tx] += add;
            __syncthreads();
        }
        if (i < nb) partial[i] = c0 + sh[tx] - v;  // exclusive global
        __syncthreads();
        if (tx == 0) carry = c0 + sh[255];
        __syncthreads();
    }
}

// finalize rowptr, distribute per-chunk cursor starts into cnt (in place)
__global__ void k_cursor(int* __restrict__ cnt, int* __restrict__ rowptr,
                         const int* __restrict__ partial, int n) {
    int i = blockIdx.x * blockDim.x + threadIdx.x;
    if (i >= n) return;
    int base = rowptr[i] + partial[i >> 8];
    rowptr[i] = base;
    int c[NCHUNK];
#pragma unroll
    for (int cc = 0; cc < NCHUNK; ++cc) c[cc] = cnt[(size_t)cc * n + i];
#pragma unroll
    for (int cc = 0; cc < NCHUNK; ++cc) {
        cnt[(size_t)cc * n + i] = base;
        base += c[cc];
    }
}

__global__ void k_position(const int* __restrict__ src, const int* __restrict__ dst,
                           int* __restrict__ cur, int* __restrict__ sorted_src,
                           int n, int e, int chunk_div) {
    int i = blockIdx.x * blockDim.x + threadIdx.x;
    if (i >= e) return;
    int c = i / chunk_div;
    int pos = atomicAdd(&cur[(size_t)c * n + dst[i]], 1);
    sorted_src[pos] = src[i];
}

// layer-1 aggregate + transform, 16 lanes per node
__global__ void k_agg1(const int* __restrict__ rowptr, const int* __restrict__ t,
                       const int* __restrict__ ss, const float* __restrict__ g1,
                       const float* __restrict__ dinv, const float* __restrict__ W1,
                       const float* __restrict__ b1, float* __restrict__ g2, int n) {
    int tid = blockIdx.x * blockDim.x + threadIdx.x;
    int node = tid >> 4;
    int lane = tid & 15;
    if (node >= n) return;
    int start = rowptr[node];
    int cnt = t[node];
    float a0 = 0, a1 = 0, a2 = 0, a3 = 0, a4 = 0;
    for (int k = lane; k < cnt; k += 16) {
        int s = ss[start + k];
        const float* gp = g1 + (size_t)s * GST;
        float4 v4 = *(const float4*)gp;
        float v5 = gp[4];
        a0 += v4.x; a1 += v4.y; a2 += v4.z; a3 += v4.w; a4 += v5;
    }
#pragma unroll
    for (int off = 1; off < 16; off <<= 1) {
        a0 += __shfl_xor(a0, off, 16);
        a1 += __shfl_xor(a1, off, 16);
        a2 += __shfl_xor(a2, off, 16);
        a3 += __shfl_xor(a3, off, 16);
        a4 += __shfl_xor(a4, off, 16);
    }
    if (lane == 0) {
        float d = dinv[node];
        const float* gi = g1 + (size_t)node * GST;
        float v[FIN];
        v[0] = (a0 + gi[0]) * d;
        v[1] = (a1 + gi[1]) * d;
        v[2] = (a2 + gi[2]) * d;
        v[3] = (a3 + gi[3]) * d;
        v[4] = (a4 + gi[4]) * d;
        float* go = g2 + (size_t)node * GST;
#pragma unroll
        for (int j = 0; j < FHID; ++j) {
            float s = b1[j];
#pragma unroll
            for (int k = 0; k < FIN; ++k) s += v[k] * W1[k * FHID + j];
            go[j] = fmaxf(s, 0.0f) * d;  // relu, pre-scale for layer 2
        }
    }
}

// layer-2 aggregate + transform + log_softmax
__global__ void k_agg2(const int* __restrict__ rowptr, const int* __restrict__ t,
                       const int* __restrict__ ss, const float* __restrict__ g2,
                       const float* __restrict__ dinv, const float* __restrict__ W2,
                       const float* __restrict__ b2, float* __restrict__ out, int n) {
    int tid = blockIdx.x * blockDim.x + threadIdx.x;
    int node = tid >> 4;
    int lane = tid & 15;
    if (node >= n) return;
    int start = rowptr[node];
    int cnt = t[node];
    float a0 = 0, a1 = 0, a2 = 0, a3 = 0, a4 = 0;
    for (int k = lane; k < cnt; k += 16) {
        int s = ss[start + k];
        const float* gp = g2 + (size_t)s * GST;
        float4 v4 = *(const float4*)gp;
        float v5 = gp[4];
        a0 += v4.x; a1 += v4.y; a2 += v4.z; a3 += v4.w; a4 += v5;
    }
#pragma unroll
    for (int off = 1; off < 16; off <<= 1) {
        a0 += __shfl_xor(a0, off, 16);
        a1 += __shfl_xor(a1, off, 16);
        a2 += __shfl_xor(a2, off, 16);
        a3 += __shfl_xor(a3, off, 16);
        a4 += __shfl_xor(a4, off, 16);
    }
    if (lane == 0) {
        float d = dinv[node];
        const float* gi = g2 + (size_t)node * GST;
        float v[FHID];
        v[0] = (a0 + gi[0]) * d;
        v[1] = (a1 + gi[1]) * d;
        v[2] = (a2 + gi[2]) * d;
        v[3] = (a3 + gi[3]) * d;
        v[4] = (a4 + gi[4]) * d;
        float o[FOUT];
        float m = -1e30f;
#pragma unroll
        for (int j = 0; j < FOUT; ++j) {
            float s = b2[j];
#pragma unroll
            for (int k = 0; k < FHID; ++k) s += v[k] * W2[k * FOUT + j];
            o[j] = s;
            m = fmaxf(m, s);
        }
        float ssum = 0.0f;
#pragma unroll
        for (int j = 0; j < FOUT; ++j) ssum += expf(o[j] - m);
        float lse = m + logf(ssum);
        float* op = out + (size_t)node * FOUT;
#pragma unroll
        for (int j = 0; j < FOUT; ++j) op[j] = o[j] - lse;
    }
}

// ---------------- fallback (R1) kernels ----------------

__global__ void f_init_deg(float* __restrict__ deg, int n) {
    int i = blockIdx.x * blockDim.x + threadIdx.x;
    if (i < n) deg[i] = 1.0f;
}
__global__ void f_count_deg(const int* __restrict__ dst, float* __restrict__ deg, int e) {
    int i = blockIdx.x * blockDim.x + threadIdx.x;
    if (i < e) atomicAdd(&deg[dst[i]], 1.0f);
}
__global__ void f_finish_deg_g1(const float* __restrict__ x, float* __restrict__ dinv,
                                float* __restrict__ g1, int n) {
    int i = blockIdx.x * blockDim.x + threadIdx.x;
    if (i >= n) return;
    float d = rsqrtf(dinv[i]);
    dinv[i] = d;
#pragma unroll
    for (int f = 0; f < FIN; ++f) g1[(size_t)i * FIN + f] = x[(size_t)i * FIN + f] * d;
}
__global__ void f_scatter5(const int* __restrict__ src, const int* __restrict__ dst,
                           const float* __restrict__ g, float* __restrict__ acc, int e) {
    int i = blockIdx.x * blockDim.x + threadIdx.x;
    if (i >= e) return;
    int s = src[i], d = dst[i];
    float* a = acc + (size_t)d * 5;
    const float* gp = g + (size_t)s * 5;
    atomicAdd(a + 0, gp[0]);
    atomicAdd(a + 1, gp[1]);
    atomicAdd(a + 2, gp[2]);
    atomicAdd(a + 3, gp[3]);
    atomicAdd(a + 4, gp[4]);
}
__global__ void f_update1(const float* __restrict__ dinv, float* __restrict__ g,
                          float* __restrict__ acc, const float* __restrict__ W1,
                          const float* __restrict__ b1, int n) {
    int i = blockIdx.x * blockDim.x + threadIdx.x;
    if (i >= n) return;
    float d = dinv[i];
    float v[FIN];
#pragma unroll
    for (int f = 0; f < FIN; ++f) {
        size_t idx = (size_t)i * FIN + f;
        v[f] = (acc[idx] + g[idx]) * d;
        acc[idx] = 0.0f;
    }
#pragma unroll
    for (int j = 0; j < FHID; ++j) {
        float s = b1[j];
#pragma unroll
        for (int k = 0; k < FIN; ++k) s += v[k] * W1[k * FHID + j];
        g[(size_t)i * FHID + j] = fmaxf(s, 0.0f) * d;
    }
}
__global__ void f_update2(const float* __restrict__ dinv, const float* __restrict__ g,
                          const float* __restrict__ acc, const float* __restrict__ W2,
                          const float* __restrict__ b2, float* __restrict__ out, int n) {
    int i = blockIdx.x * blockDim.x + threadIdx.x;
    if (i >= n) return;
    float d = dinv[i];
    float v[FHID];
#pragma unroll
    for (int f = 0; f < FHID; ++f) v[f] = (acc[(size_t)i * FHID + f] + g[(size_t)i * FHID + f]) * d;
    float o[FOUT];
    float m = -1e30f;
#pragma unroll
    for (int j = 0; j < FOUT; ++j) {
        float s = b2[j];
#pragma unroll
        for (int k = 0; k < FHID; ++k) s += v[k] * W2[k * FOUT + j];
        o[j] = s;
        m = fmaxf(m, s);
    }
    float ssum = 0.0f;
#pragma unroll
    for (int j = 0; j < FOUT; ++j) ssum += expf(o[j] - m);
    float lse = m + logf(ssum);
#pragma unroll
    for (int j = 0; j < FOUT; ++j) out[(size_t)i * FOUT + j] = o[j] - lse;
}

// ---------------- launcher ----------------

extern "C" void kernel_launch(void* const* d_in, const int* in_sizes, int n_in,
                              void* d_out, int out_size, void* d_ws, size_t ws_size,
                              hipStream_t stream) {
    const float* x  = (const float*)d_in[0];
    const int*   ei = (const int*)d_in[1];
    const float* W1 = (const float*)d_in[2];
    const float* b1 = (const float*)d_in[3];
    const float* W2 = (const float*)d_in[4];
    const float* b2 = (const float*)d_in[5];

    const int n = in_sizes[0] / FIN;   // 500,000
    const int e = in_sizes[1] / 2;     // 16,000,000
    const int* src = ei;
    const int* dst = ei + e;

    const int B = 256;
    const int gn = (n + B - 1) / B;
    const int ge = (e + B - 1) / B;
    const int nb1 = gn;  // scan1 blocks

    // main-path ws layout (bytes, all 16B-aligned given n,e multiples)
    size_t off = 0;
    int*   cnt    = (int*)((char*)d_ws + off); off += (size_t)NCHUNK * n * 4;  // hist -> cursors
    int*   t      = (int*)((char*)d_ws + off); off += (size_t)n * 4;           // real-edge counts
    int*   rowptr = (int*)((char*)d_ws + off); off += (size_t)n * 4;
    float* dinv   = (float*)((char*)d_ws + off); off += (size_t)n * 4;
    float* g1     = (float*)((char*)d_ws + off); off += (size_t)GST * n * 4;
    float* g2     = (float*)((char*)d_ws + off); off += (size_t)GST * n * 4;
    int*   ss     = (int*)((char*)d_ws + off); off += (size_t)e * 4;           // sorted src
    int*   part   = (int*)((char*)d_ws + off); off += (size_t)nb1 * 4;
    size_t need = off;

    if (ws_size >= need) {
        const int chunk_div = (e + NCHUNK - 1) / NCHUNK;
        hipMemsetAsync(cnt, 0, (size_t)NCHUNK * n * 4, stream);
        k_hist<<<ge, B, 0, stream>>>(dst, cnt, n, e, chunk_div);
        k_sumdeg<<<gn, B, 0, stream>>>(cnt, x, t, dinv, g1, n);
        k_scan1<<<nb1, B, 0, stream>>>(t, rowptr, part, n);
        k_scan2<<<1, B, 0, stream>>>(part, nb1);
        k_cursor<<<gn, B, 0, stream>>>(cnt, rowptr, part, n);
        k_position<<<ge, B, 0, stream>>>(src, dst, cnt, ss, n, e, chunk_div);
        const int ga = ((size_t)n * 16 + B - 1) / B;
        k_agg1<<<ga, B, 0, stream>>>(rowptr, t, ss, g1, dinv, W1, b1, g2, n);
        k_agg2<<<ga, B, 0, stream>>>(rowptr, t, ss, g2, dinv, W2, b2, (float*)d_out, n);
    } else {
        // R1 fallback: atomic scatter (needs 11n floats = 22 MB)
        float* fdinv = (float*)d_ws;
        float* fg    = fdinv + n;
        float* facc  = fg + (size_t)5 * n;
        hipMemsetAsync(facc, 0, (size_t)5 * n * sizeof(float), stream);
        f_init_deg<<<gn, B, 0, stream>>>(fdinv, n);
        f_count_deg<<<ge, B, 0, stream>>>(dst, fdinv, e);
        f_finish_deg_g1<<<gn, B, 0, stream>>>(x, fdinv, fg, n);
        f_scatter5<<<ge, B, 0, stream>>>(src, dst, fg, facc, e);
        f_update1<<<gn, B, 0, stream>>>(fdinv, fg, facc, W1, b1, n);
        f_scatter5<<<ge, B, 0, stream>>>(src, dst, fg, facc, e);
        f_update2<<<gn, B, 0, stream>>>(fdinv, fg, facc, W2, b2, (float*)d_out, n);
    }
}

// Round 3
// 1200.017 us; speedup vs baseline: 7.2073x; 1.9728x over previous
//
#include <hip/hip_runtime.h>
#include <math.h>

// GCN 2-layer, N=500k, E=16M, F 5->5->8.
// R3: bucket-binned edges (256 nodes/bucket), all atomics in LDS.
//   binhist -> scan -> binscatter (packed u32 edges, contiguous runs per
//   (block,bucket)) -> per-bucket {deg+g1, agg1, agg2} with LDS accumulators
//   and fused dense epilogues. Zero global atomics.
// Fallback to R1 atomic-scatter path if ws/n limits exceeded.

#define FIN 5
#define FHID 5
#define FOUT 8
#define GST 8        // padded feature row stride (32 B, aligned single-line gathers)
#define RB 256       // nodes per bucket (== block size)
#define EPB 16384    // edges per binning block
#define NBUCK_MAX 2048

// ---------- binning ----------

__global__ void k_binhist(const int* __restrict__ dst, int* __restrict__ cnt,
                          int e, int nbuck, int nblkE) {
    __shared__ int hist[NBUCK_MAX];
    int tx = threadIdx.x, blk = blockIdx.x;
    for (int b = tx; b < nbuck; b += 256) hist[b] = 0;
    __syncthreads();
    size_t base = (size_t)blk * EPB;
    for (int k = 0; k < EPB; k += 256) {
        size_t i = base + k + tx;
        if (i < (size_t)e) atomicAdd(&hist[dst[i] >> 8], 1);
    }
    __syncthreads();
    for (int b = tx; b < nbuck; b += 256) cnt[(size_t)b * nblkE + blk] = hist[b];
}

// generic block-local exclusive scan: scn = excl-within-block, part[blk] = block sum
__global__ void k_scan1(const int* __restrict__ t, int* __restrict__ scn,
                        int* __restrict__ partial, int n) {
    __shared__ int sh[256];
    int tx = threadIdx.x;
    int i = blockIdx.x * 256 + tx;
    int v = (i < n) ? t[i] : 0;
    sh[tx] = v;
    __syncthreads();
    for (int off = 1; off < 256; off <<= 1) {
        int add = (tx >= off) ? sh[tx - off] : 0;
        __syncthreads();
        sh[tx] += add;
        __syncthreads();
    }
    if (i < n) scn[i] = sh[tx] - v;
    if (tx == 255) partial[blockIdx.x] = sh[255];
}

// single-block exclusive scan of partial[nb] in place (looped, carry)
__global__ void k_scan2(int* __restrict__ partial, int nb) {
    __shared__ int sh[256];
    __shared__ int carry;
    int tx = threadIdx.x;
    if (tx == 0) carry = 0;
    __syncthreads();
    for (int base = 0; base < nb; base += 256) {
        int i = base + tx;
        int v = (i < nb) ? partial[i] : 0;
        int c0 = carry;
        sh[tx] = v;
        __syncthreads();
        for (int off = 1; off < 256; off <<= 1) {
            int add = (tx >= off) ? sh[tx - off] : 0;
            __syncthreads();
            sh[tx] += add;
            __syncthreads();
        }
        if (i < nb) partial[i] = c0 + sh[tx] - v;
        __syncthreads();
        if (tx == 0) carry = c0 + sh[255];
        __syncthreads();
    }
}

__global__ void k_binscatter(const int* __restrict__ src, const int* __restrict__ dst,
                             const int* __restrict__ scn, const int* __restrict__ part,
                             unsigned int* __restrict__ binned,
                             int e, int nbuck, int nblkE) {
    __shared__ int cur[NBUCK_MAX];
    int tx = threadIdx.x, blk = blockIdx.x;
    for (int b = tx; b < nbuck; b += 256) {
        size_t idx = (size_t)b * nblkE + blk;
        cur[b] = scn[idx] + part[idx >> 8];
    }
    __syncthreads();
    size_t base = (size_t)blk * EPB;
    for (int k = 0; k < EPB; k += 256) {
        size_t i = base + k + tx;
        if (i < (size_t)e) {
            int d = dst[i];
            int pos = atomicAdd(&cur[d >> 8], 1);
            binned[pos] = ((unsigned int)(d & (RB - 1)) << 24) | (unsigned int)src[i];
        }
    }
}

// ---------- per-bucket passes ----------

__device__ __forceinline__ void bucket_range(const int* __restrict__ scn,
                                             const int* __restrict__ part,
                                             int b, int nbuck, int nblkE, int e,
                                             int& start, int& end) {
    size_t i0 = (size_t)b * nblkE;
    start = scn[i0] + part[i0 >> 8];
    if (b + 1 < nbuck) {
        size_t i1 = (size_t)(b + 1) * nblkE;
        end = scn[i1] + part[i1 >> 8];
    } else {
        end = e;
    }
}

// degree (LDS count) -> dinv, g1 = x * dinv (padded stride GST)
__global__ void k_deg_g(const unsigned int* __restrict__ binned,
                        const int* __restrict__ scn, const int* __restrict__ part,
                        const float* __restrict__ x, float* __restrict__ dinv,
                        float* __restrict__ g1, int n, int e, int nbuck, int nblkE) {
    __shared__ int cnt[RB];
    int tx = threadIdx.x, b = blockIdx.x;
    cnt[tx] = 0;
    __syncthreads();
    int start, end;
    bucket_range(scn, part, b, nbuck, nblkE, e, start, end);
    for (int i = start + tx; i < end; i += 256)
        atomicAdd(&cnt[binned[i] >> 24], 1);
    __syncthreads();
    int node = b * RB + tx;
    if (node < n) {
        float d = rsqrtf((float)(cnt[tx] + 1));  // +1 self-loop
        dinv[node] = d;
        float* gp = g1 + (size_t)node * GST;
        const float* xp = x + (size_t)node * FIN;
#pragma unroll
        for (int f = 0; f < FIN; ++f) gp[f] = xp[f] * d;
    }
}

// layer 1: LDS-accumulate gathered g1 over bucket, fused W1+relu, g2 = h*dinv
__global__ void k_bagg1(const unsigned int* __restrict__ binned,
                        const int* __restrict__ scn, const int* __restrict__ part,
                        const float* __restrict__ g1, const float* __restrict__ dinv,
                        const float* __restrict__ W1, const float* __restrict__ b1,
                        float* __restrict__ g2, int n, int e, int nbuck, int nblkE) {
    __shared__ float acc[FIN * RB];  // feature-major: acc[f*RB + dl]
    int tx = threadIdx.x, b = blockIdx.x;
#pragma unroll
    for (int f = 0; f < FIN; ++f) acc[f * RB + tx] = 0.0f;
    __syncthreads();
    int start, end;
    bucket_range(scn, part, b, nbuck, nblkE, e, start, end);
    for (int i = start + tx; i < end; i += 256) {
        unsigned int p = binned[i];
        int s = (int)(p & 0xFFFFFF);
        int dl = (int)(p >> 24);
        const float* gp = g1 + (size_t)s * GST;
        float4 v4 = *(const float4*)gp;
        float v5 = gp[4];
        atomicAdd(&acc[dl], v4.x);
        atomicAdd(&acc[RB + dl], v4.y);
        atomicAdd(&acc[2 * RB + dl], v4.z);
        atomicAdd(&acc[3 * RB + dl], v4.w);
        atomicAdd(&acc[4 * RB + dl], v5);
    }
    __syncthreads();
    int node = b * RB + tx;
    if (node >= n) return;
    float d = dinv[node];
    const float* gi = g1 + (size_t)node * GST;
    float v[FIN];
#pragma unroll
    for (int f = 0; f < FIN; ++f) v[f] = (acc[f * RB + tx] + gi[f]) * d;
    float* go = g2 + (size_t)node * GST;
#pragma unroll
    for (int j = 0; j < FHID; ++j) {
        float s = b1[j];
#pragma unroll
        for (int k = 0; k < FIN; ++k) s = fmaf(v[k], W1[k * FHID + j], s);
        go[j] = fmaxf(s, 0.0f) * d;  // relu, pre-scaled for layer 2
    }
}

// layer 2: LDS-accumulate gathered g2, fused W2 + log_softmax
__global__ void k_bagg2(const unsigned int* __restrict__ binned,
                        const int* __restrict__ scn, const int* __restrict__ part,
                        const float* __restrict__ g2, const float* __restrict__ dinv,
                        const float* __restrict__ W2, const float* __restrict__ b2,
                        float* __restrict__ out, int n, int e, int nbuck, int nblkE) {
    __shared__ float acc[FHID * RB];
    int tx = threadIdx.x, b = blockIdx.x;
#pragma unroll
    for (int f = 0; f < FHID; ++f) acc[f * RB + tx] = 0.0f;
    __syncthreads();
    int start, end;
    bucket_range(scn, part, b, nbuck, nblkE, e, start, end);
    for (int i = start + tx; i < end; i += 256) {
        unsigned int p = binned[i];
        int s = (int)(p & 0xFFFFFF);
        int dl = (int)(p >> 24);
        const float* gp = g2 + (size_t)s * GST;
        float4 v4 = *(const float4*)gp;
        float v5 = gp[4];
        atomicAdd(&acc[dl], v4.x);
        atomicAdd(&acc[RB + dl], v4.y);
        atomicAdd(&acc[2 * RB + dl], v4.z);
        atomicAdd(&acc[3 * RB + dl], v4.w);
        atomicAdd(&acc[4 * RB + dl], v5);
    }
    __syncthreads();
    int node = b * RB + tx;
    if (node >= n) return;
    float d = dinv[node];
    const float* gi = g2 + (size_t)node * GST;
    float v[FHID];
#pragma unroll
    for (int f = 0; f < FHID; ++f) v[f] = (acc[f * RB + tx] + gi[f]) * d;
    float o[FOUT];
    float m = -1e30f;
#pragma unroll
    for (int j = 0; j < FOUT; ++j) {
        float s = b2[j];
#pragma unroll
        for (int k = 0; k < FHID; ++k) s = fmaf(v[k], W2[k * FOUT + j], s);
        o[j] = s;
        m = fmaxf(m, s);
    }
    float ssum = 0.0f;
#pragma unroll
    for (int j = 0; j < FOUT; ++j) ssum += expf(o[j] - m);
    float lse = m + logf(ssum);
    float* op = out + (size_t)node * FOUT;
#pragma unroll
    for (int j = 0; j < FOUT; ++j) op[j] = o[j] - lse;
}

// ---------- fallback (R1) ----------

__global__ void f_init_deg(float* __restrict__ deg, int n) {
    int i = blockIdx.x * blockDim.x + threadIdx.x;
    if (i < n) deg[i] = 1.0f;
}
__global__ void f_count_deg(const int* __restrict__ dst, float* __restrict__ deg, int e) {
    int i = blockIdx.x * blockDim.x + threadIdx.x;
    if (i < e) atomicAdd(&deg[dst[i]], 1.0f);
}
__global__ void f_finish_deg_g1(const float* __restrict__ x, float* __restrict__ dinv,
                                float* __restrict__ g1, int n) {
    int i = blockIdx.x * blockDim.x + threadIdx.x;
    if (i >= n) return;
    float d = rsqrtf(dinv[i]);
    dinv[i] = d;
#pragma unroll
    for (int f = 0; f < FIN; ++f) g1[(size_t)i * FIN + f] = x[(size_t)i * FIN + f] * d;
}
__global__ void f_scatter5(const int* __restrict__ src, const int* __restrict__ dst,
                           const float* __restrict__ g, float* __restrict__ acc, int e) {
    int i = blockIdx.x * blockDim.x + threadIdx.x;
    if (i >= e) return;
    int s = src[i], d = dst[i];
    float* a = acc + (size_t)d * 5;
    const float* gp = g + (size_t)s * 5;
    atomicAdd(a + 0, gp[0]);
    atomicAdd(a + 1, gp[1]);
    atomicAdd(a + 2, gp[2]);
    atomicAdd(a + 3, gp[3]);
    atomicAdd(a + 4, gp[4]);
}
__global__ void f_update1(const float* __restrict__ dinv, float* __restrict__ g,
                          float* __restrict__ acc, const float* __restrict__ W1,
                          const float* __restrict__ b1, int n) {
    int i = blockIdx.x * blockDim.x + threadIdx.x;
    if (i >= n) return;
    float d = dinv[i];
    float v[FIN];
#pragma unroll
    for (int f = 0; f < FIN; ++f) {
        size_t idx = (size_t)i * FIN + f;
        v[f] = (acc[idx] + g[idx]) * d;
        acc[idx] = 0.0f;
    }
#pragma unroll
    for (int j = 0; j < FHID; ++j) {
        float s = b1[j];
#pragma unroll
        for (int k = 0; k < FIN; ++k) s += v[k] * W1[k * FHID + j];
        g[(size_t)i * FHID + j] = fmaxf(s, 0.0f) * d;
    }
}
__global__ void f_update2(const float* __restrict__ dinv, const float* __restrict__ g,
                          const float* __restrict__ acc, const float* __restrict__ W2,
                          const float* __restrict__ b2, float* __restrict__ out, int n) {
    int i = blockIdx.x * blockDim.x + threadIdx.x;
    if (i >= n) return;
    float d = dinv[i];
    float v[FHID];
#pragma unroll
    for (int f = 0; f < FHID; ++f) v[f] = (acc[(size_t)i * FHID + f] + g[(size_t)i * FHID + f]) * d;
    float o[FOUT];
    float m = -1e30f;
#pragma unroll
    for (int j = 0; j < FOUT; ++j) {
        float s = b2[j];
#pragma unroll
        for (int k = 0; k < FHID; ++k) s += v[k] * W2[k * FOUT + j];
        o[j] = s;
        m = fmaxf(m, s);
    }
    float ssum = 0.0f;
#pragma unroll
    for (int j = 0; j < FOUT; ++j) ssum += expf(o[j] - m);
    float lse = m + logf(ssum);
#pragma unroll
    for (int j = 0; j < FOUT; ++j) out[(size_t)i * FOUT + j] = o[j] - lse;
}

// ---------- launcher ----------

extern "C" void kernel_launch(void* const* d_in, const int* in_sizes, int n_in,
                              void* d_out, int out_size, void* d_ws, size_t ws_size,
                              hipStream_t stream) {
    const float* x  = (const float*)d_in[0];
    const int*   ei = (const int*)d_in[1];
    const float* W1 = (const float*)d_in[2];
    const float* b1 = (const float*)d_in[3];
    const float* W2 = (const float*)d_in[4];
    const float* b2 = (const float*)d_in[5];

    const int n = in_sizes[0] / FIN;   // 500,000
    const int e = in_sizes[1] / 2;     // 16,000,000
    const int* src = ei;
    const int* dst = ei + e;

    const int nbuck = (n + RB - 1) / RB;          // 1954
    const int nblkE = (e + EPB - 1) / EPB;        // 977
    const size_t m = (size_t)nbuck * nblkE;       // ~1.9M
    const int nsb = (int)((m + 255) / 256);       // scan1 blocks

    // ws layout (16B-aligned slices)
    size_t off = 0;
    auto alloc = [&](size_t bytes) { size_t o = off; off = (off + bytes + 15) & ~(size_t)15; return o; };
    int*          cnt    = (int*)((char*)d_ws + alloc(m * 4));
    int*          scn    = (int*)((char*)d_ws + alloc(m * 4));
    int*          part   = (int*)((char*)d_ws + alloc((size_t)nsb * 4));
    float*        dinv   = (float*)((char*)d_ws + alloc((size_t)n * 4));
    float*        g1     = (float*)((char*)d_ws + alloc((size_t)GST * n * 4));
    float*        g2     = (float*)((char*)d_ws + alloc((size_t)GST * n * 4));
    unsigned int* binned = (unsigned int*)((char*)d_ws + alloc((size_t)e * 4));
    const size_t need = off;

    const int B = 256;

    if (ws_size >= need && n <= (1 << 24) && nbuck <= NBUCK_MAX) {
        k_binhist<<<nblkE, B, 0, stream>>>(dst, cnt, e, nbuck, nblkE);
        k_scan1<<<nsb, B, 0, stream>>>(cnt, scn, part, (int)m);
        k_scan2<<<1, B, 0, stream>>>(part, nsb);
        k_binscatter<<<nblkE, B, 0, stream>>>(src, dst, scn, part, binned, e, nbuck, nblkE);
        k_deg_g<<<nbuck, B, 0, stream>>>(binned, scn, part, x, dinv, g1, n, e, nbuck, nblkE);
        k_bagg1<<<nbuck, B, 0, stream>>>(binned, scn, part, g1, dinv, W1, b1, g2, n, e, nbuck, nblkE);
        k_bagg2<<<nbuck, B, 0, stream>>>(binned, scn, part, g2, dinv, W2, b2, (float*)d_out, n, e, nbuck, nblkE);
    } else {
        // R1 fallback (22 MB ws)
        const int gn = (n + B - 1) / B;
        const int ge = (e + B - 1) / B;
        float* fdinv = (float*)d_ws;
        float* fg    = fdinv + n;
        float* facc  = fg + (size_t)5 * n;
        hipMemsetAsync(facc, 0, (size_t)5 * n * sizeof(float), stream);
        f_init_deg<<<gn, B, 0, stream>>>(fdinv, n);
        f_count_deg<<<ge, B, 0, stream>>>(dst, fdinv, e);
        f_finish_deg_g1<<<gn, B, 0, stream>>>(x, fdinv, fg, n);
        f_scatter5<<<ge, B, 0, stream>>>(src, dst, fg, facc, e);
        f_update1<<<gn, B, 0, stream>>>(fdinv, fg, facc, W1, b1, n);
        f_scatter5<<<ge, B, 0, stream>>>(src, dst, fg, facc, e);
        f_update2<<<gn, B, 0, stream>>>(fdinv, fg, facc, W2, b2, (float*)d_out, n);
    }
}